// Round 6
// baseline (708.748 us; speedup 1.0000x reference)
//
#include <hip/hip_runtime.h>

typedef unsigned short u16;
typedef unsigned int   u32;
typedef __attribute__((ext_vector_type(8))) short short8;
typedef __attribute__((ext_vector_type(4))) float float4v;

// ---------- helpers ----------
__device__ __forceinline__ float bf2f(u16 u){ union{u32 i; float f;} c; c.i = ((u32)u) << 16; return c.f; }
__device__ __forceinline__ float bflo(u32 u){ union{u32 i; float f;} c; c.i = u << 16; return c.f; }
__device__ __forceinline__ float bfhi(u32 u){ union{u32 i; float f;} c; c.i = u & 0xFFFF0000u; return c.f; }
__device__ __forceinline__ u16 f2bf(float f){
  union{float f; u32 i;} c; c.f = f; u32 x = c.i;
  return (u16)((x + 0x7FFFu + ((x >> 16) & 1u)) >> 16);   // RNE
}
__device__ __forceinline__ u32 pack2(float a, float b){ return (u32)f2bf(a) | ((u32)f2bf(b) << 16); }

__device__ __forceinline__ void async16(const void* g, void* l){
  __builtin_amdgcn_global_load_lds((const __attribute__((address_space(1))) void*)g,
                                   (__attribute__((address_space(3))) void*)l, 16, 0, 0);
}

// ---------- fp32 -> bf16 bulk convert ----------
__global__ void f32_to_bf16(const float* __restrict__ src, u16* __restrict__ dst, int n4)
{
  int stride = gridDim.x * 256;
  for (int i = blockIdx.x * 256 + threadIdx.x; i < n4; i += stride) {
    float4 v = ((const float4*)src)[i];
    ushort4 o; o.x = f2bf(v.x); o.y = f2bf(v.y); o.z = f2bf(v.z); o.w = f2bf(v.w);
    ((ushort4*)dst)[i] = o;
  }
}

// ---------- prep: Wqk = [wq_w; wk_w] rows as-is (B^T layout), bf16; bias fp32 ----------
__global__ void prep_qkw(const float* __restrict__ wq, const float* __restrict__ wk,
                         const float* __restrict__ wqb, const float* __restrict__ wkb,
                         u16* __restrict__ Wqk, float* __restrict__ biasQK)
{
  int t = blockIdx.x * 256 + threadIdx.x;
  int stride = gridDim.x * 256;
  for (int i = t; i < 294912; i += stride) {       // 1536*768/4
    float4 v = (i < 147456) ? ((const float4*)wq)[i] : ((const float4*)wk)[i - 147456];
    ushort4 o; o.x = f2bf(v.x); o.y = f2bf(v.y); o.z = f2bf(v.z); o.w = f2bf(v.w);
    ((ushort4*)Wqk)[i] = o;
  }
  if (t < 768) biasQK[t] = wqb[t];
  else if (t < 1536) biasQK[t] = wkb[t - 768];
}

// gcnT[l][o][d] = gcn[l][d][o], fp32 -> bf16
__global__ void prep_gcnT(const float* __restrict__ gcn, u16* __restrict__ gcnT)
{
  __shared__ float tile[32][33];
  int l = blockIdx.z;
  int d0 = blockIdx.y * 32, o0 = blockIdx.x * 32;
  int tx = threadIdx.x, ty = threadIdx.y;           // 32 x 8
  const float* src = gcn + (size_t)l * 589824;
  u16* dst = gcnT + (size_t)l * 589824;
  for (int i = 0; i < 32; i += 8) tile[ty + i][tx] = src[(size_t)(d0 + ty + i) * 768 + o0 + tx];
  __syncthreads();
  for (int i = 0; i < 32; i += 8) dst[(size_t)(o0 + ty + i) * 768 + d0 + tx] = f2bf(tile[tx][ty + i]);
}

// ---------- main GEMM: C[m][n] = sum_k A[m][k]*B[n][k] + bias[n] ----------
// 128x128 tile, BK=32, global_load_lds width-16 staging with XOR chunk swizzle:
// 16B chunk (row, q) stored at LDS slot s = q ^ ((row>>1)&3)  ->  fragment reads
// land 2 lanes/bank (free) instead of 8-way conflicts with the naive layout.
__global__ void __launch_bounds__(256) gemm_bt(const u16* __restrict__ A, const u16* __restrict__ Bw,
                                               const float* __restrict__ bias, u16* __restrict__ C,
                                               int M, int N, int K)
{
  __shared__ __attribute__((aligned(16))) u16 As[128 * 32];
  __shared__ __attribute__((aligned(16))) u16 Bs[128 * 32];
  int tid = threadIdx.x, lane = tid & 63, wid = tid >> 6;
  int wm = wid >> 1, wn = wid & 1;
  size_t m0 = (size_t)blockIdx.x * 128, n0 = (size_t)blockIdx.y * 128;

  float4v acc[4][4];
  for (int r = 0; r < 4; r++) for (int c = 0; c < 4; c++) acc[r][c] = (float4v){0.f, 0.f, 0.f, 0.f};

  // staging: lane l of wave w fills LDS bytes 2048*w + 16*l  -> (row = 32w + l/4, slot = l&3)
  // fetch the global chunk q = slot ^ ((row>>1)&3) = (l&3) ^ ((l>>3)&3)
  int srow = 32 * wid + (lane >> 2);
  int sq   = (lane & 3) ^ ((lane >> 3) & 3);
  const u16* gA = A  + (m0 + srow) * (size_t)K + sq * 8;
  const u16* gB = Bw + (n0 + srow) * (size_t)K + sq * 8;
  u16* lA = &As[1024 * wid];
  u16* lB = &Bs[1024 * wid];

  int l15 = lane & 15;
  int rs  = (lane >> 4) ^ ((lane >> 1) & 3);        // read slot: want chunk q=lane>>4 of row ..+l15

  for (int kt = 0; kt < K; kt += 32) {
    async16(gA + kt, lA);
    async16(gA + kt + (size_t)16 * K, lA + 512);
    async16(gB + kt, lB);
    async16(gB + kt + (size_t)16 * K, lB + 512);
    __syncthreads();
    short8 af[4], bfr[4];
    for (int r = 0; r < 4; r++) af[r]  = *(const short8*)&As[(wm * 64 + r * 16 + l15) * 32 + rs * 8];
    for (int c = 0; c < 4; c++) bfr[c] = *(const short8*)&Bs[(wn * 64 + c * 16 + l15) * 32 + rs * 8];
    for (int r = 0; r < 4; r++)
      for (int c = 0; c < 4; c++)
        acc[r][c] = __builtin_amdgcn_mfma_f32_16x16x32_bf16(af[r], bfr[c], acc[r][c], 0, 0, 0);
    __syncthreads();
  }

  int quad = lane >> 4;
  for (int c = 0; c < 4; c++) {
    int n = (int)n0 + wn * 64 + c * 16 + l15;
    float bv = bias ? bias[n] : 0.f;
    for (int r = 0; r < 4; r++) {
      size_t mbase = m0 + wm * 64 + r * 16 + quad * 4;
      for (int t = 0; t < 4; t++)
        C[(mbase + t) * (size_t)N + n] = f2bf(acc[r][c][t] + bv);
    }
  }
}

// ---------- batched dot + square + L1-normalize: adj[g][i][j] (same XOR swizzle) ----------
template<int NPAD>
__global__ void __launch_bounds__(256) dot_adj(const u16* __restrict__ QK, float* __restrict__ adj, int n)
{
  constexpr int CT = NPAD / 16;
  __shared__ __attribute__((aligned(16))) u16 As[NPAD * 32];
  __shared__ __attribute__((aligned(16))) u16 Bs[NPAD * 32];
  int g = blockIdx.x, tid = threadIdx.x, lane = tid & 63, wid = tid >> 6;

  float4v acc[CT];
  for (int c = 0; c < CT; c++) acc[c] = (float4v){0.f, 0.f, 0.f, 0.f};

  int row = tid >> 2, kq = tid & 3;
  int wslot = kq ^ ((row >> 1) & 3);
  int l15 = lane & 15;
  int rslot = (lane >> 4) ^ ((lane >> 1) & 3);
  for (int kt = 0; kt < 768; kt += 32) {
    uint4 va = {0,0,0,0}, vb = {0,0,0,0};
    if (tid < NPAD * 4 && row < n) {
      const u16* base = QK + ((size_t)g * n + row) * 1536 + kt + kq * 8;
      va = *(const uint4*)base;
      vb = *(const uint4*)(base + 768);
    }
    __syncthreads();
    if (tid < NPAD * 4) {
      ((uint4*)As)[row * 4 + wslot] = va;
      ((uint4*)Bs)[row * 4 + wslot] = vb;
    }
    __syncthreads();
    if (wid < CT) {
      short8 a = *(const short8*)&As[(wid * 16 + l15) * 32 + rslot * 8];
      for (int ct = 0; ct < CT; ct++) {
        short8 b = *(const short8*)&Bs[(ct * 16 + l15) * 32 + rslot * 8];
        acc[ct] = __builtin_amdgcn_mfma_f32_16x16x32_bf16(a, b, acc[ct], 0, 0, 0);
      }
    }
  }

  if (wid < CT) {
    int quad = lane >> 4;
    float* adjg = adj + (size_t)g * NPAD * NPAD;
    float rsum[4];
    for (int r = 0; r < 4; r++) {
      float s = 0.f;
      for (int ct = 0; ct < CT; ct++) { float v = acc[ct][r]; s += v * v; }
      s += __shfl_xor(s, 1); s += __shfl_xor(s, 2); s += __shfl_xor(s, 4); s += __shfl_xor(s, 8);
      rsum[r] = 1.0f / fmaxf(s, 1e-12f);
    }
    for (int ct = 0; ct < CT; ct++)
      for (int r = 0; r < 4; r++) {
        float v = acc[ct][r];
        int rrow = wid * 16 + quad * 4 + r, col = ct * 16 + l15;
        adjg[(size_t)rrow * NPAD + col] = v * v * rsum[r];
      }
  }
}

// ---------- fused adj@H + LayerNorm + ReLU -> bf16 (ROWS rows per block) ----------
// grid (G, n/ROWS), block 384 (2 d-cols/thread). H[g] read n/ROWS times instead of n/4.
template<int ROWS, int NPAD>
__global__ void __launch_bounds__(384) adjH_ln(const float* __restrict__ adj, const u16* __restrict__ H,
                                               const float* __restrict__ lng, const float* __restrict__ lnb,
                                               u16* __restrict__ out, int n, int layer)
{
  __shared__ float adjr[ROWS][NPAD];
  __shared__ float red[6][ROWS][2];
  __shared__ float bc[ROWS][2];
  int g = blockIdx.x, i0 = blockIdx.y * ROWS;
  int tid = threadIdx.x, wid = tid >> 6, lane = tid & 63;

  for (int idx = tid; idx < ROWS * NPAD; idx += 384) {
    int ii = idx / NPAD, j = idx & (NPAD - 1);
    adjr[ii][j] = adj[((size_t)g * NPAD + (i0 + ii)) * NPAD + j];
  }
  __syncthreads();

  int d0 = tid * 2;
  float a0[ROWS], a1[ROWS];
#pragma unroll
  for (int ii = 0; ii < ROWS; ii++) { a0[ii] = 0.f; a1[ii] = 0.f; }
  const u32* hp = (const u32*)H + (size_t)g * n * 384 + tid;
  for (int j = 0; j < n; j++) {
    u32 u = hp[(size_t)j * 384];
    float h0 = bflo(u), h1 = bfhi(u);
#pragma unroll
    for (int ii = 0; ii < ROWS; ii++) { float a = adjr[ii][j]; a0[ii] += a * h0; a1[ii] += a * h1; }
  }

#pragma unroll
  for (int ii = 0; ii < ROWS; ii++) {
    float s = a0[ii] + a1[ii];
    float q = a0[ii] * a0[ii] + a1[ii] * a1[ii];
    for (int m = 1; m <= 32; m <<= 1) { s += __shfl_xor(s, m); q += __shfl_xor(q, m); }
    if (lane == 0) { red[wid][ii][0] = s; red[wid][ii][1] = q; }
  }
  __syncthreads();
  if (tid < ROWS) {
    float s = 0.f, q = 0.f;
    for (int w = 0; w < 6; w++) { s += red[w][tid][0]; q += red[w][tid][1]; }
    float mu = s * (1.f / 768.f);
    float var = q * (1.f / 768.f) - mu * mu;
    bc[tid][0] = mu; bc[tid][1] = rsqrtf(fmaxf(var, 0.f) + 1e-5f);
  }
  __syncthreads();

  float lg0 = lng[layer * 768 + d0], lg1 = lng[layer * 768 + d0 + 1];
  float lb0 = lnb[layer * 768 + d0], lb1 = lnb[layer * 768 + d0 + 1];
#pragma unroll
  for (int ii = 0; ii < ROWS; ii++) {
    int i = i0 + ii;
    float mu = bc[ii][0], rsi = bc[ii][1];
    float v0 = fmaxf((a0[ii] - mu) * rsi * lg0 + lb0, 0.f);
    float v1 = fmaxf((a1[ii] - mu) * rsi * lg1 + lb1, 0.f);
    *(u32*)&out[((size_t)g * n + i) * 768 + d0] = pack2(v0, v1);
  }
}

// ---------- mean over nodes -> bf16 [G][768] ----------
__global__ void __launch_bounds__(384) mean_nodes(const u16* __restrict__ X, u16* __restrict__ out,
                                                  int n, float inv)
{
  int g = blockIdx.x, tid = threadIdx.x;
  const u32* p = (const u32*)X + (size_t)g * n * 384 + tid;
  float s0 = 0.f, s1 = 0.f;
  for (int j = 0; j < n; j++) { u32 u = p[(size_t)j * 384]; s0 += bflo(u); s1 += bfhi(u); }
  ((u32*)out)[(size_t)g * 384 + tid] = pack2(s0 * inv, s1 * inv);
}

// ---------- frame mean (bf16 in) + concat fgs (fp32) -> y fp32 (in d_out) ----------
__global__ void __launch_bounds__(384) frame_mean_concat(const u16* __restrict__ X2f,
                                                         const float* __restrict__ fgs, float* __restrict__ yout)
{
  int b = blockIdx.x, tid = threadIdx.x;
  const u32* p = (const u32*)X2f + (size_t)b * 32 * 384 + tid;
  float s0 = 0.f, s1 = 0.f;
  for (int j = 0; j < 32; j++) { u32 u = p[(size_t)j * 384]; s0 += bflo(u); s1 += bfhi(u); }
  int d0 = tid * 2;
  yout[(size_t)b * 1536 + d0]     = s0 * (1.f / 32.f);
  yout[(size_t)b * 1536 + d0 + 1] = s1 * (1.f / 32.f);
  yout[(size_t)b * 1536 + 768 + d0]     = fgs[(size_t)b * 768 + d0];
  yout[(size_t)b * 1536 + 768 + d0 + 1] = fgs[(size_t)b * 768 + d0 + 1];
}

// ---------- classifier: fc1+relu, wide grid (192 blocks x 4 outputs) ----------
__global__ void __launch_bounds__(256) fc1_relu(const float* __restrict__ yout,
                                                const float* __restrict__ fc1w, const float* __restrict__ fc1b,
                                                float* __restrict__ h)
{
  int o = blockIdx.x * 4 + (threadIdx.x >> 6);
  int lane = threadIdx.x & 63;
  float acc[16];
  for (int b = 0; b < 16; b++) acc[b] = 0.f;
  const float4* wr = (const float4*)(fc1w + (size_t)o * 1536);
  for (int k4 = lane; k4 < 384; k4 += 64) {
    float4 wv = wr[k4];
    for (int b = 0; b < 16; b++) {
      float4 yv = ((const float4*)(yout + (size_t)b * 1536))[k4];
      acc[b] += wv.x * yv.x + wv.y * yv.y + wv.z * yv.z + wv.w * yv.w;
    }
  }
  for (int m = 1; m <= 32; m <<= 1)
    for (int b = 0; b < 16; b++) acc[b] += __shfl_xor(acc[b], m);
  if (lane < 16) h[(size_t)lane * 768 + o] = fmaxf(acc[lane] + fc1b[o], 0.f);
}

// ---------- classifier: fc2, wide grid (100 blocks x 4 outputs) ----------
__global__ void __launch_bounds__(256) fc2_out(const float* __restrict__ h,
                                               const float* __restrict__ fc2w, const float* __restrict__ fc2b,
                                               float* __restrict__ logits)
{
  int o = blockIdx.x * 4 + (threadIdx.x >> 6);
  int lane = threadIdx.x & 63;
  float acc[16];
  for (int b = 0; b < 16; b++) acc[b] = 0.f;
  const float4* wr = (const float4*)(fc2w + (size_t)o * 768);
  for (int k4 = lane; k4 < 192; k4 += 64) {
    float4 wv = wr[k4];
    for (int b = 0; b < 16; b++) {
      float4 hv = ((const float4*)(h + (size_t)b * 768))[k4];
      acc[b] += wv.x * hv.x + wv.y * hv.y + wv.z * hv.z + wv.w * hv.w;
    }
  }
  for (int m = 1; m <= 32; m <<= 1)
    for (int b = 0; b < 16; b++) acc[b] += __shfl_xor(acc[b], m);
  if (lane < 16) logits[(size_t)lane * 400 + o] = acc[lane] + fc2b[o];
}

// ---------- launch ----------
extern "C" void kernel_launch(void* const* d_in, const int* in_sizes, int n_in,
                              void* d_out, int out_size, void* d_ws, size_t ws_size,
                              hipStream_t stream) {
  const float* feats = (const float*)d_in[0];
  const float* fgs   = (const float*)d_in[1];
  const float* wq_w  = (const float*)d_in[3];
  const float* wq_b  = (const float*)d_in[4];
  const float* wk_w  = (const float*)d_in[5];
  const float* wk_b  = (const float*)d_in[6];
  const float* gcn_w = (const float*)d_in[7];
  const float* ln_g  = (const float*)d_in[8];
  const float* ln_b  = (const float*)d_in[9];
  const float* fc1_w = (const float*)d_in[10];
  const float* fc1_b = (const float*)d_in[11];
  const float* fc2_w = (const float*)d_in[12];
  const float* fc2_b = (const float*)d_in[13];
  float* out  = (float*)d_out;
  float* yout = out + 16 * 400;               // y region: [16][1536] fp32

  char* ws = (char*)d_ws;
  size_t off = 0;
  auto alloc = [&](size_t b){ size_t r = off; off = (off + b + 255) & ~(size_t)255; return r; };
  // persistent buffers (~47 MB)
  u16*  Fb     = (u16*) (ws + alloc((size_t)25600 * 768 * 2));   // feats as bf16
  u16*  Wqk    = (u16*) (ws + alloc((size_t)1536 * 768 * 2));
  u16*  gcnT   = (u16*) (ws + alloc((size_t)2 * 768 * 768 * 2));
  float* biasQK= (float*)(ws + alloc((size_t)1536 * 4));
  u16*  Xf     = (u16*) (ws + alloc((size_t)512 * 768 * 2));
  u16*  QKf    = (u16*) (ws + alloc((size_t)512 * 1536 * 2));
  u16*  Hf     = (u16*) (ws + alloc((size_t)512 * 768 * 2));
  u16*  X1f    = (u16*) (ws + alloc((size_t)512 * 768 * 2));
  u16*  X2f    = (u16*) (ws + alloc((size_t)512 * 768 * 2));
  float* adjF  = (float*)(ws + alloc((size_t)16 * 32 * 32 * 4));
  float* hbuf  = (float*)(ws + alloc((size_t)16 * 768 * 4));
  size_t base = off;

  // object-level chunk size by ws budget (ws_size constant -> graph-safe)
  auto need = [&](int GC){ return base + (size_t)GC * 50 * 1536 * 2 + 512 + (size_t)GC * 64 * 64 * 4 + 512; };
  int GC = 64;
  if (need(512) <= ws_size) GC = 512;
  else if (need(256) <= ws_size) GC = 256;
  else if (need(128) <= ws_size) GC = 128;
  int R = GC * 50;
  size_t off2 = base;
  auto alloc2 = [&](size_t b){ size_t r = off2; off2 = (off2 + b + 255) & ~(size_t)255; return r; };
  u16*  QKc  = (u16*) (ws + alloc2((size_t)R * 1536 * 2));
  float* adjO = (float*)(ws + alloc2((size_t)GC * 64 * 64 * 4));
  u16* Hc  = QKc;                        // [R][768] (QK dead after dot_adj)
  u16* X1c = QKc + (size_t)R * 768;
  u16* H2c = QKc;
  u16* X2c = QKc + (size_t)R * 768;

  // prep
  f32_to_bf16<<<4800, 256, 0, stream>>>(feats, Fb, 25600 * 768 / 4);
  prep_qkw<<<288, 256, 0, stream>>>(wq_w, wk_w, wq_b, wk_b, Wqk, biasQK);
  prep_gcnT<<<dim3(24, 24, 2), dim3(32, 8), 0, stream>>>(gcn_w, gcnT);

  // ---- object-level graph (512 graphs of n=50), chunked ----
  int nchunks = 512 / GC;
  for (int c = 0; c < nchunks; c++) {
    const u16* fc = Fb + (size_t)c * GC * 50 * 768;
    gemm_bt<<<dim3(R / 128, 12), 256, 0, stream>>>(fc, Wqk, biasQK, QKc, R, 1536, 768);
    dot_adj<64><<<GC, 256, 0, stream>>>(QKc, adjO, 50);
    gemm_bt<<<dim3(R / 128, 6), 256, 0, stream>>>(fc, gcnT, nullptr, Hc, R, 768, 768);
    adjH_ln<25, 64><<<dim3(GC, 2), 384, 0, stream>>>(adjO, Hc, ln_g, ln_b, X1c, 50, 0);
    gemm_bt<<<dim3(R / 128, 6), 256, 0, stream>>>(X1c, gcnT + (size_t)768 * 768, nullptr, H2c, R, 768, 768);
    adjH_ln<25, 64><<<dim3(GC, 2), 384, 0, stream>>>(adjO, H2c, ln_g, ln_b, X2c, 50, 1);
    mean_nodes<<<GC, 384, 0, stream>>>(X2c, Xf + (size_t)c * GC * 768, 50, 1.f / 50.f);
  }

  // ---- frame-level graph (16 graphs of n=32) ----
  gemm_bt<<<dim3(4, 12), 256, 0, stream>>>(Xf, Wqk, biasQK, QKf, 512, 1536, 768);
  dot_adj<32><<<16, 256, 0, stream>>>(QKf, adjF, 32);
  gemm_bt<<<dim3(4, 6), 256, 0, stream>>>(Xf, gcnT, nullptr, Hf, 512, 768, 768);
  adjH_ln<16, 32><<<dim3(16, 2), 384, 0, stream>>>(adjF, Hf, ln_g, ln_b, X1f, 32, 0);
  gemm_bt<<<dim3(4, 6), 256, 0, stream>>>(X1f, gcnT + (size_t)768 * 768, nullptr, Hf, 512, 768, 768);
  adjH_ln<16, 32><<<dim3(16, 2), 384, 0, stream>>>(adjF, Hf, ln_g, ln_b, X2f, 32, 1);

  // ---- head ----
  frame_mean_concat<<<16, 384, 0, stream>>>(X2f, fgs, yout);
  fc1_relu<<<192, 256, 0, stream>>>(yout, fc1_w, fc1_b, hbuf);
  fc2_out<<<100, 256, 0, stream>>>(hbuf, fc2_w, fc2_b, out);
}

// Round 7
// 586.191 us; speedup vs baseline: 1.2091x; 1.2091x over previous
//
#include <hip/hip_runtime.h>

typedef unsigned short u16;
typedef unsigned int   u32;
typedef __attribute__((ext_vector_type(8))) short short8;
typedef __attribute__((ext_vector_type(4))) float float4v;

// ---------- helpers ----------
__device__ __forceinline__ float bf2f(u16 u){ union{u32 i; float f;} c; c.i = ((u32)u) << 16; return c.f; }
__device__ __forceinline__ float bflo(u32 u){ union{u32 i; float f;} c; c.i = u << 16; return c.f; }
__device__ __forceinline__ float bfhi(u32 u){ union{u32 i; float f;} c; c.i = u & 0xFFFF0000u; return c.f; }
__device__ __forceinline__ u16 f2bf(float f){
  union{float f; u32 i;} c; c.f = f; u32 x = c.i;
  return (u16)((x + 0x7FFFu + ((x >> 16) & 1u)) >> 16);   // RNE
}
__device__ __forceinline__ u32 pack2(float a, float b){ return (u32)f2bf(a) | ((u32)f2bf(b) << 16); }

__device__ __forceinline__ void async16(const void* g, void* l){
  __builtin_amdgcn_global_load_lds((const __attribute__((address_space(1))) void*)g,
                                   (__attribute__((address_space(3))) void*)l, 16, 0, 0);
}

// ---------- fp32 -> bf16 bulk convert ----------
__global__ void f32_to_bf16(const float* __restrict__ src, u16* __restrict__ dst, int n4)
{
  int stride = gridDim.x * 256;
  for (int i = blockIdx.x * 256 + threadIdx.x; i < n4; i += stride) {
    float4 v = ((const float4*)src)[i];
    ushort4 o; o.x = f2bf(v.x); o.y = f2bf(v.y); o.z = f2bf(v.z); o.w = f2bf(v.w);
    ((ushort4*)dst)[i] = o;
  }
}

// ---------- prep: Wqk = [wq_w; wk_w] rows (B^T layout) bf16; bias fp32 ----------
__global__ void prep_qkw(const float* __restrict__ wq, const float* __restrict__ wk,
                         const float* __restrict__ wqb, const float* __restrict__ wkb,
                         u16* __restrict__ Wqk, float* __restrict__ biasQK)
{
  int t = blockIdx.x * 256 + threadIdx.x;
  int stride = gridDim.x * 256;
  for (int i = t; i < 294912; i += stride) {
    float4 v = (i < 147456) ? ((const float4*)wq)[i] : ((const float4*)wk)[i - 147456];
    ushort4 o; o.x = f2bf(v.x); o.y = f2bf(v.y); o.z = f2bf(v.z); o.w = f2bf(v.w);
    ((ushort4*)Wqk)[i] = o;
  }
  if (t < 768) biasQK[t] = wqb[t];
  else if (t < 1536) biasQK[t] = wkb[t - 768];
}

// gcnT[l][o][d] = gcn[l][d][o], fp32 -> bf16
__global__ void prep_gcnT(const float* __restrict__ gcn, u16* __restrict__ gcnT)
{
  __shared__ float tile[32][33];
  int l = blockIdx.z;
  int d0 = blockIdx.y * 32, o0 = blockIdx.x * 32;
  int tx = threadIdx.x, ty = threadIdx.y;           // 32 x 8
  const float* src = gcn + (size_t)l * 589824;
  u16* dst = gcnT + (size_t)l * 589824;
  for (int i = 0; i < 32; i += 8) tile[ty + i][tx] = src[(size_t)(d0 + ty + i) * 768 + o0 + tx];
  __syncthreads();
  for (int i = 0; i < 32; i += 8) dst[(size_t)(o0 + ty + i) * 768 + d0 + tx] = f2bf(tile[tx][ty + i]);
}

// ---------- main GEMM (R6 version: async16 + XOR swizzle, 0 bank conflicts) ----------
__global__ void __launch_bounds__(256) gemm_bt(const u16* __restrict__ A, const u16* __restrict__ Bw,
                                               const float* __restrict__ bias, u16* __restrict__ C,
                                               int M, int N, int K)
{
  __shared__ __attribute__((aligned(16))) u16 As[128 * 32];
  __shared__ __attribute__((aligned(16))) u16 Bs[128 * 32];
  int tid = threadIdx.x, lane = tid & 63, wid = tid >> 6;
  int wm = wid >> 1, wn = wid & 1;
  size_t m0 = (size_t)blockIdx.x * 128, n0 = (size_t)blockIdx.y * 128;

  float4v acc[4][4];
  for (int r = 0; r < 4; r++) for (int c = 0; c < 4; c++) acc[r][c] = (float4v){0.f, 0.f, 0.f, 0.f};

  int srow = 32 * wid + (lane >> 2);
  int sq   = (lane & 3) ^ ((lane >> 3) & 3);
  const u16* gA = A  + (m0 + srow) * (size_t)K + sq * 8;
  const u16* gB = Bw + (n0 + srow) * (size_t)K + sq * 8;
  u16* lA = &As[1024 * wid];
  u16* lB = &Bs[1024 * wid];

  int l15 = lane & 15;
  int rs  = (lane >> 4) ^ ((lane >> 1) & 3);

  for (int kt = 0; kt < K; kt += 32) {
    async16(gA + kt, lA);
    async16(gA + kt + (size_t)16 * K, lA + 512);
    async16(gB + kt, lB);
    async16(gB + kt + (size_t)16 * K, lB + 512);
    __syncthreads();
    short8 af[4], bfr[4];
    for (int r = 0; r < 4; r++) af[r]  = *(const short8*)&As[(wm * 64 + r * 16 + l15) * 32 + rs * 8];
    for (int c = 0; c < 4; c++) bfr[c] = *(const short8*)&Bs[(wn * 64 + c * 16 + l15) * 32 + rs * 8];
    for (int r = 0; r < 4; r++)
      for (int c = 0; c < 4; c++)
        acc[r][c] = __builtin_amdgcn_mfma_f32_16x16x32_bf16(af[r], bfr[c], acc[r][c], 0, 0, 0);
    __syncthreads();
  }

  int quad = lane >> 4;
  for (int c = 0; c < 4; c++) {
    int n = (int)n0 + wn * 64 + c * 16 + l15;
    float bv = bias ? bias[n] : 0.f;
    for (int r = 0; r < 4; r++) {
      size_t mbase = m0 + wm * 64 + r * 16 + quad * 4;
      for (int t = 0; t < 4; t++)
        C[(mbase + t) * (size_t)N + n] = f2bf(acc[r][c][t] + bv);
    }
  }
}

// ================= fused per-graph adjacency kernels =================
// One block (512 thr, 8 waves) per graph.
// L1: S=Q.K^T (MFMA) -> adj=L1norm(S^2) (LDS bf16 + global store) -> X1=relu(LN(adj@H))
// L2: load adj -> relu(LN(adj@H2)) -> column mean only.
// LDS strides padded to 72 u16 (16B-aligned rows, 2-way banks = free).

template<int NP>
__global__ void __launch_bounds__(512) fused_l1(const u16* __restrict__ QK, const u16* __restrict__ H,
                                                const float* __restrict__ lng, const float* __restrict__ lnb,
                                                u16* __restrict__ adjG, u16* __restrict__ X, int n)
{
  constexpr int ST = 72;              // u16 stride
  constexpr int SF = 66;              // f32 stride
  constexpr int S_TPW  = (NP == 64) ? 2 : 1;
  constexpr int S2_TPW = (NP == 64) ? 2 : 1;
  __shared__ __attribute__((aligned(16))) u16 Aq[NP * 32];
  __shared__ __attribute__((aligned(16))) u16 Bk[NP * 32];
  __shared__ __attribute__((aligned(16))) float Sq[NP * SF];
  __shared__ __attribute__((aligned(16))) u16 adjb[NP * ST];
  __shared__ __attribute__((aligned(16))) u16 HT[64 * ST];
  __shared__ float rsum[NP];
  __shared__ float stats[NP][2];
  __shared__ float bc[NP][2];
  __shared__ float lg[768], lb[768];

  int g = blockIdx.x;
  int tid = threadIdx.x, lane = tid & 63, w = tid >> 6;
  int l15 = lane & 15, quad = lane >> 4;

  for (int i = tid; i < 768; i += 512) { lg[i] = lng[i]; lb[i] = lnb[i]; }
  if (tid < NP) { stats[tid][0] = 0.f; stats[tid][1] = 0.f; }

  // ---- stage 1: S = Q @ K^T ----
  int sidx = tid & (NP * 4 - 1);
  int srow = sidx >> 2, skq = sidx & 3;
  int wslot = skq ^ ((srow >> 1) & 3);
  bool isB = tid >= NP * 4;
  bool sact = tid < NP * 8;
  const u16* gbase = QK + ((size_t)g * n + srow) * 1536 + skq * 8 + (isB ? 768 : 0);

  int s_mt, s_nt0; bool s_act;
  if (NP == 64) { s_mt = w & 3; s_nt0 = (w >> 2) * 2; s_act = true; }
  else          { s_mt = w >> 1; s_nt0 = w & 1;       s_act = (w < 4); }

  int rslot = (lane >> 4) ^ ((lane >> 1) & 3);
  float4v sacc[S_TPW];
  for (int j = 0; j < S_TPW; j++) sacc[j] = (float4v){0.f, 0.f, 0.f, 0.f};

  for (int kt = 0; kt < 768; kt += 32) {
    uint4 v = {0, 0, 0, 0};
    if (sact && srow < n) v = *(const uint4*)(gbase + kt);
    __syncthreads();
    if (sact) ((uint4*)(isB ? Bk : Aq))[srow * 4 + wslot] = v;
    __syncthreads();
    if (s_act) {
      short8 a = *(const short8*)&Aq[(s_mt * 16 + l15) * 32 + rslot * 8];
      for (int j = 0; j < S_TPW; j++) {
        short8 b = *(const short8*)&Bk[((s_nt0 + j) * 16 + l15) * 32 + rslot * 8];
        sacc[j] = __builtin_amdgcn_mfma_f32_16x16x32_bf16(a, b, sacc[j], 0, 0, 0);
      }
    }
  }
  __syncthreads();
  if (s_act)
    for (int j = 0; j < S_TPW; j++)
      for (int t = 0; t < 4; t++) {
        int row = s_mt * 16 + quad * 4 + t, col = (s_nt0 + j) * 16 + l15;
        float v = sacc[j][t];
        Sq[row * SF + col] = v * v;
      }
  __syncthreads();
  if (tid < NP) {
    float s = 0.f;
    for (int j = 0; j < NP; j++) s += Sq[tid * SF + j];
    rsum[tid] = 1.0f / fmaxf(s, 1e-12f);
  }
  __syncthreads();
  if (tid * 8 < NP * NP) {
    int row = (tid * 8) / NP, c0 = (tid * 8) % NP;
    float rsv = rsum[row];
    u32* gadj = (u32*)(adjG + (size_t)g * NP * NP);
    for (int p = 0; p < 4; p++) {
      u32 o = pack2(Sq[row * SF + c0 + 2 * p] * rsv, Sq[row * SF + c0 + 2 * p + 1] * rsv);
      *(u32*)&adjb[row * ST + c0 + 2 * p] = o;
      gadj[(row * NP + c0) / 2 + p] = o;
    }
  }

  // ---- stage 2: X = adj @ H ----
  int m2, nt20;
  if (NP == 64) { m2 = w & 3; nt20 = (w >> 2) * 2; }
  else          { m2 = w & 1; nt20 = w >> 1; }

  float4v xacc[12][S2_TPW];
#pragma unroll
  for (int ch = 0; ch < 12; ch++) for (int j = 0; j < S2_TPW; j++) xacc[ch][j] = (float4v){0.f,0.f,0.f,0.f};

  int hj = tid >> 3, hseg = tid & 7;
#pragma unroll
  for (int ch = 0; ch < 12; ch++) {
    __syncthreads();
    if (tid < NP * 8) {
      uint4 hv = {0, 0, 0, 0};
      if (hj < n) hv = *(const uint4*)(H + ((size_t)g * n + hj) * 768 + ch * 64 + hseg * 8);
      const u16* ep = (const u16*)&hv;
      for (int i = 0; i < 8; i++) HT[(hseg * 8 + i) * ST + hj] = ep[i];
    }
    __syncthreads();
    for (int k = 0; k < NP / 32; k++) {
      short8 a = *(const short8*)&adjb[(m2 * 16 + l15) * ST + k * 32 + quad * 8];
      for (int j = 0; j < S2_TPW; j++) {
        short8 b = *(const short8*)&HT[((nt20 + j) * 16 + l15) * ST + k * 32 + quad * 8];
        xacc[ch][j] = __builtin_amdgcn_mfma_f32_16x16x32_bf16(a, b, xacc[ch][j], 0, 0, 0);
      }
    }
  }

  // ---- LN stats ----
  float ssum[4] = {0,0,0,0}, ssq[4] = {0,0,0,0};
#pragma unroll
  for (int ch = 0; ch < 12; ch++)
    for (int j = 0; j < S2_TPW; j++)
      for (int t = 0; t < 4; t++) { float v = xacc[ch][j][t]; ssum[t] += v; ssq[t] += v * v; }
  for (int m = 1; m <= 8; m <<= 1)
    for (int t = 0; t < 4; t++) { ssum[t] += __shfl_xor(ssum[t], m); ssq[t] += __shfl_xor(ssq[t], m); }
  if (l15 == 0)
    for (int t = 0; t < 4; t++) {
      atomicAdd(&stats[m2 * 16 + quad * 4 + t][0], ssum[t]);
      atomicAdd(&stats[m2 * 16 + quad * 4 + t][1], ssq[t]);
    }
  __syncthreads();
  if (tid < NP) {
    float mu = stats[tid][0] * (1.f / 768.f);
    float var = stats[tid][1] * (1.f / 768.f) - mu * mu;
    bc[tid][0] = mu; bc[tid][1] = rsqrtf(fmaxf(var, 0.f) + 1e-5f);
  }
  __syncthreads();

  // ---- LN + relu + write X ----
#pragma unroll
  for (int ch = 0; ch < 12; ch++)
    for (int j = 0; j < S2_TPW; j++)
      for (int t = 0; t < 4; t++) {
        int row = m2 * 16 + quad * 4 + t;
        if (row < n) {
          int d = ch * 64 + (nt20 + j) * 16 + l15;
          float v = fmaxf((xacc[ch][j][t] - bc[row][0]) * bc[row][1] * lg[d] + lb[d], 0.f);
          X[((size_t)g * n + row) * 768 + d] = f2bf(v);
        }
      }
}

template<int NP>
__global__ void __launch_bounds__(512) fused_l2(const u16* __restrict__ adjG, const u16* __restrict__ H,
                                                const float* __restrict__ lng, const float* __restrict__ lnb,
                                                u16* __restrict__ Xmean, int n, float inv)
{
  constexpr int ST = 72;
  constexpr int S2_TPW = (NP == 64) ? 2 : 1;
  __shared__ __attribute__((aligned(16))) u16 adjb[NP * ST];
  __shared__ __attribute__((aligned(16))) u16 HT[64 * ST];
  __shared__ float stats[NP][2];
  __shared__ float bc[NP][2];
  __shared__ float colsum[768];
  __shared__ float lg[768], lb[768];

  int g = blockIdx.x;
  int tid = threadIdx.x, lane = tid & 63, w = tid >> 6;
  int l15 = lane & 15, quad = lane >> 4;

  for (int i = tid; i < 768; i += 512) { lg[i] = lng[i]; lb[i] = lnb[i]; colsum[i] = 0.f; }
  if (tid < NP) { stats[tid][0] = 0.f; stats[tid][1] = 0.f; }
  if (tid * 8 < NP * NP) {
    int row = (tid * 8) / NP, c0 = (tid * 8) % NP;
    const u32* gadj = (const u32*)(adjG + (size_t)g * NP * NP);
    for (int p = 0; p < 4; p++)
      *(u32*)&adjb[row * ST + c0 + 2 * p] = gadj[(row * NP + c0) / 2 + p];
  }

  int m2, nt20;
  if (NP == 64) { m2 = w & 3; nt20 = (w >> 2) * 2; }
  else          { m2 = w & 1; nt20 = w >> 1; }

  float4v xacc[12][S2_TPW];
#pragma unroll
  for (int ch = 0; ch < 12; ch++) for (int j = 0; j < S2_TPW; j++) xacc[ch][j] = (float4v){0.f,0.f,0.f,0.f};

  int hj = tid >> 3, hseg = tid & 7;
#pragma unroll
  for (int ch = 0; ch < 12; ch++) {
    __syncthreads();
    if (tid < NP * 8) {
      uint4 hv = {0, 0, 0, 0};
      if (hj < n) hv = *(const uint4*)(H + ((size_t)g * n + hj) * 768 + ch * 64 + hseg * 8);
      const u16* ep = (const u16*)&hv;
      for (int i = 0; i < 8; i++) HT[(hseg * 8 + i) * ST + hj] = ep[i];
    }
    __syncthreads();
    for (int k = 0; k < NP / 32; k++) {
      short8 a = *(const short8*)&adjb[(m2 * 16 + l15) * ST + k * 32 + quad * 8];
      for (int j = 0; j < S2_TPW; j++) {
        short8 b = *(const short8*)&HT[((nt20 + j) * 16 + l15) * ST + k * 32 + quad * 8];
        xacc[ch][j] = __builtin_amdgcn_mfma_f32_16x16x32_bf16(a, b, xacc[ch][j], 0, 0, 0);
      }
    }
  }

  float ssum[4] = {0,0,0,0}, ssq[4] = {0,0,0,0};
#pragma unroll
  for (int ch = 0; ch < 12; ch++)
    for (int j = 0; j < S2_TPW; j++)
      for (int t = 0; t < 4; t++) { float v = xacc[ch][j][t]; ssum[t] += v; ssq[t] += v * v; }
  for (int m = 1; m <= 8; m <<= 1)
    for (int t = 0; t < 4; t++) { ssum[t] += __shfl_xor(ssum[t], m); ssq[t] += __shfl_xor(ssq[t], m); }
  if (l15 == 0)
    for (int t = 0; t < 4; t++) {
      atomicAdd(&stats[m2 * 16 + quad * 4 + t][0], ssum[t]);
      atomicAdd(&stats[m2 * 16 + quad * 4 + t][1], ssq[t]);
    }
  __syncthreads();
  if (tid < NP) {
    float mu = stats[tid][0] * (1.f / 768.f);
    float var = stats[tid][1] * (1.f / 768.f) - mu * mu;
    bc[tid][0] = mu; bc[tid][1] = rsqrtf(fmaxf(var, 0.f) + 1e-5f);
  }
  __syncthreads();

  // LN + relu + column-mean accumulate (merge 4 quads via shfl, 1 atomic per 4 rows)
#pragma unroll
  for (int ch = 0; ch < 12; ch++)
    for (int j = 0; j < S2_TPW; j++)
      for (int t = 0; t < 4; t++) {
        int row = m2 * 16 + quad * 4 + t;
        int d = ch * 64 + (nt20 + j) * 16 + l15;
        float v = fmaxf((xacc[ch][j][t] - bc[row][0]) * bc[row][1] * lg[d] + lb[d], 0.f);
        float vm = (row < n) ? v : 0.f;
        vm += __shfl_xor(vm, 16);
        vm += __shfl_xor(vm, 32);
        if (quad == 0) atomicAdd(&colsum[d], vm);
      }
  __syncthreads();
  if (tid < 384)
    ((u32*)Xmean)[(size_t)g * 384 + tid] = pack2(colsum[tid * 2] * inv, colsum[tid * 2 + 1] * inv);
}

// ---------- concat: y = [bf2f(Xm) ; fgs] fp32 (in d_out) ----------
__global__ void __launch_bounds__(384) concat_y(const u16* __restrict__ Xm,
                                                const float* __restrict__ fgs, float* __restrict__ yout)
{
  int b = blockIdx.x, tid = threadIdx.x;
  u32 u = ((const u32*)Xm)[(size_t)b * 384 + tid];
  int d0 = tid * 2;
  yout[(size_t)b * 1536 + d0]     = bflo(u);
  yout[(size_t)b * 1536 + d0 + 1] = bfhi(u);
  yout[(size_t)b * 1536 + 768 + d0]     = fgs[(size_t)b * 768 + d0];
  yout[(size_t)b * 1536 + 768 + d0 + 1] = fgs[(size_t)b * 768 + d0 + 1];
}

// ---------- classifier ----------
__global__ void __launch_bounds__(256) fc1_relu(const float* __restrict__ yout,
                                                const float* __restrict__ fc1w, const float* __restrict__ fc1b,
                                                float* __restrict__ h)
{
  int o = blockIdx.x * 4 + (threadIdx.x >> 6);
  int lane = threadIdx.x & 63;
  float acc[16];
  for (int b = 0; b < 16; b++) acc[b] = 0.f;
  const float4* wr = (const float4*)(fc1w + (size_t)o * 1536);
  for (int k4 = lane; k4 < 384; k4 += 64) {
    float4 wv = wr[k4];
    for (int b = 0; b < 16; b++) {
      float4 yv = ((const float4*)(yout + (size_t)b * 1536))[k4];
      acc[b] += wv.x * yv.x + wv.y * yv.y + wv.z * yv.z + wv.w * yv.w;
    }
  }
  for (int m = 1; m <= 32; m <<= 1)
    for (int b = 0; b < 16; b++) acc[b] += __shfl_xor(acc[b], m);
  if (lane < 16) h[(size_t)lane * 768 + o] = fmaxf(acc[lane] + fc1b[o], 0.f);
}

__global__ void __launch_bounds__(256) fc2_out(const float* __restrict__ h,
                                               const float* __restrict__ fc2w, const float* __restrict__ fc2b,
                                               float* __restrict__ logits)
{
  int o = blockIdx.x * 4 + (threadIdx.x >> 6);
  int lane = threadIdx.x & 63;
  float acc[16];
  for (int b = 0; b < 16; b++) acc[b] = 0.f;
  const float4* wr = (const float4*)(fc2w + (size_t)o * 768);
  for (int k4 = lane; k4 < 192; k4 += 64) {
    float4 wv = wr[k4];
    for (int b = 0; b < 16; b++) {
      float4 hv = ((const float4*)(h + (size_t)b * 768))[k4];
      acc[b] += wv.x * hv.x + wv.y * hv.y + wv.z * hv.z + wv.w * hv.w;
    }
  }
  for (int m = 1; m <= 32; m <<= 1)
    for (int b = 0; b < 16; b++) acc[b] += __shfl_xor(acc[b], m);
  if (lane < 16) logits[(size_t)lane * 400 + o] = acc[lane] + fc2b[o];
}

// ---------- launch ----------
extern "C" void kernel_launch(void* const* d_in, const int* in_sizes, int n_in,
                              void* d_out, int out_size, void* d_ws, size_t ws_size,
                              hipStream_t stream) {
  const float* feats = (const float*)d_in[0];
  const float* fgs   = (const float*)d_in[1];
  const float* wq_w  = (const float*)d_in[3];
  const float* wq_b  = (const float*)d_in[4];
  const float* wk_w  = (const float*)d_in[5];
  const float* wk_b  = (const float*)d_in[6];
  const float* gcn_w = (const float*)d_in[7];
  const float* ln_g  = (const float*)d_in[8];
  const float* ln_b  = (const float*)d_in[9];
  const float* fc1_w = (const float*)d_in[10];
  const float* fc1_b = (const float*)d_in[11];
  const float* fc2_w = (const float*)d_in[12];
  const float* fc2_b = (const float*)d_in[13];
  float* out  = (float*)d_out;
  float* yout = out + 16 * 400;               // y region: [16][1536] fp32

  char* ws = (char*)d_ws;
  size_t off = 0;
  auto alloc = [&](size_t b){ size_t r = off; off = (off + b + 255) & ~(size_t)255; return r; };
  // persistent buffers (~48 MB)
  u16*  Fb     = (u16*) (ws + alloc((size_t)25600 * 768 * 2));   // feats bf16
  u16*  Wqk    = (u16*) (ws + alloc((size_t)1536 * 768 * 2));
  u16*  gcnT   = (u16*) (ws + alloc((size_t)2 * 768 * 768 * 2));
  float* biasQK= (float*)(ws + alloc((size_t)1536 * 4));
  u16*  Xf     = (u16*) (ws + alloc((size_t)512 * 768 * 2));
  u16*  QKf    = (u16*) (ws + alloc((size_t)512 * 1536 * 2));
  u16*  Hf     = (u16*) (ws + alloc((size_t)512 * 768 * 2));
  u16*  X1f    = (u16*) (ws + alloc((size_t)512 * 768 * 2));
  u16*  adjFb  = (u16*) (ws + alloc((size_t)16 * 32 * 32 * 2));
  u16*  Xm     = (u16*) (ws + alloc((size_t)16 * 768 * 2));
  float* hbuf  = (float*)(ws + alloc((size_t)16 * 768 * 4));
  size_t base = off;

  // per-chunk: QKc [R][1536] + Hc [R][768] + adjG [GC][64][64] bf16
  auto need = [&](int GC){
    size_t R = (size_t)GC * 50;
    return base + R * 1536 * 2 + 512 + R * 768 * 2 + 512 + (size_t)GC * 64 * 64 * 2 + 512;
  };
  int GC = 64;
  if (need(512) <= ws_size) GC = 512;
  else if (need(256) <= ws_size) GC = 256;
  else if (need(128) <= ws_size) GC = 128;
  int R = GC * 50;
  size_t off2 = base;
  auto alloc2 = [&](size_t b){ size_t r = off2; off2 = (off2 + b + 255) & ~(size_t)255; return r; };
  u16* QKc  = (u16*)(ws + alloc2((size_t)R * 1536 * 2));
  u16* Hc   = (u16*)(ws + alloc2((size_t)R * 768 * 2));
  u16* adjGc= (u16*)(ws + alloc2((size_t)GC * 64 * 64 * 2));
  u16* X1c  = QKc;                 // QK dead after fused_l1
  u16* H2c  = Hc;                  // H1 dead after fused_l1

  // prep
  f32_to_bf16<<<4800, 256, 0, stream>>>(feats, Fb, 25600 * 768 / 4);
  prep_qkw<<<288, 256, 0, stream>>>(wq_w, wk_w, wq_b, wk_b, Wqk, biasQK);
  prep_gcnT<<<dim3(24, 24, 2), dim3(32, 8), 0, stream>>>(gcn_w, gcnT);

  // ---- object-level graph (512 graphs of n=50), chunked ----
  int nchunks = 512 / GC;
  for (int c = 0; c < nchunks; c++) {
    const u16* fc = Fb + (size_t)c * GC * 50 * 768;
    gemm_bt<<<dim3(R / 128, 12), 256, 0, stream>>>(fc, Wqk, biasQK, QKc, R, 1536, 768);
    gemm_bt<<<dim3(R / 128, 6), 256, 0, stream>>>(fc, gcnT, nullptr, Hc, R, 768, 768);
    fused_l1<64><<<GC, 512, 0, stream>>>(QKc, Hc, ln_g, ln_b, adjGc, X1c, 50);
    gemm_bt<<<dim3(R / 128, 6), 256, 0, stream>>>(X1c, gcnT + (size_t)768 * 768, nullptr, H2c, R, 768, 768);
    fused_l2<64><<<GC, 512, 0, stream>>>(adjGc, H2c, ln_g + 768, ln_b + 768,
                                         Xf + (size_t)c * GC * 768, 50, 1.f / 50.f);
  }

  // ---- frame-level graph (16 graphs of n=32) ----
  gemm_bt<<<dim3(4, 12), 256, 0, stream>>>(Xf, Wqk, biasQK, QKf, 512, 1536, 768);
  gemm_bt<<<dim3(4, 6), 256, 0, stream>>>(Xf, gcnT, nullptr, Hf, 512, 768, 768);
  fused_l1<32><<<16, 512, 0, stream>>>(QKf, Hf, ln_g, ln_b, adjFb, X1f, 32);
  gemm_bt<<<dim3(4, 6), 256, 0, stream>>>(X1f, gcnT + (size_t)768 * 768, nullptr, Hf, 512, 768, 768);
  fused_l2<32><<<16, 512, 0, stream>>>(adjFb, Hf, ln_g + 768, ln_b + 768, Xm, 32, 1.f / 32.f);

  // ---- head ----
  concat_y<<<16, 384, 0, stream>>>(Xm, fgs, yout);
  fc1_relu<<<192, 256, 0, stream>>>(yout, fc1_w, fc1_b, hbuf);
  fc2_out<<<100, 256, 0, stream>>>(hbuf, fc2_w, fc2_b, out);
}

// Round 8
// 570.601 us; speedup vs baseline: 1.2421x; 1.0273x over previous
//
#include <hip/hip_runtime.h>

typedef unsigned short u16;
typedef unsigned int   u32;
typedef __attribute__((ext_vector_type(8))) short short8;
typedef __attribute__((ext_vector_type(4))) float float4v;

// ---------- helpers ----------
__device__ __forceinline__ float bf2f(u16 u){ union{u32 i; float f;} c; c.i = ((u32)u) << 16; return c.f; }
__device__ __forceinline__ float bflo(u32 u){ union{u32 i; float f;} c; c.i = u << 16; return c.f; }
__device__ __forceinline__ float bfhi(u32 u){ union{u32 i; float f;} c; c.i = u & 0xFFFF0000u; return c.f; }
__device__ __forceinline__ u16 f2bf(float f){
  union{float f; u32 i;} c; c.f = f; u32 x = c.i;
  return (u16)((x + 0x7FFFu + ((x >> 16) & 1u)) >> 16);   // RNE
}
__device__ __forceinline__ u32 pack2(float a, float b){ return (u32)f2bf(a) | ((u32)f2bf(b) << 16); }

__device__ __forceinline__ void async16(const void* g, void* l){
  __builtin_amdgcn_global_load_lds((const __attribute__((address_space(1))) void*)g,
                                   (__attribute__((address_space(3))) void*)l, 16, 0, 0);
}

// ---------- prep: QHB rows 0-1535 = [wq_w; wk_w] bf16; bias[2304] fp32 (0 beyond 1536) ----------
__global__ void prep_qkw(const float* __restrict__ wq, const float* __restrict__ wk,
                         const float* __restrict__ wqb, const float* __restrict__ wkb,
                         u16* __restrict__ QHB, float* __restrict__ biasQH)
{
  int t = blockIdx.x * 256 + threadIdx.x;
  int stride = gridDim.x * 256;
  for (int i = t; i < 294912; i += stride) {
    float4 v = (i < 147456) ? ((const float4*)wq)[i] : ((const float4*)wk)[i - 147456];
    ushort4 o; o.x = f2bf(v.x); o.y = f2bf(v.y); o.z = f2bf(v.z); o.w = f2bf(v.w);
    ((ushort4*)QHB)[i] = o;
  }
  if (t < 768) biasQH[t] = wqb[t];
  else if (t < 1536) biasQH[t] = wkb[t - 768];
  else if (t < 2304) biasQH[t] = 0.f;
}

// gcn_w[l][d][o] -> l==0: QHB rows 1536+o ; l==1: gcnT1[o][d]   (fp32 -> bf16, transposed)
__global__ void prep_gcnT(const float* __restrict__ gcn, u16* __restrict__ QHB, u16* __restrict__ gcnT1)
{
  __shared__ float tile[32][33];
  int l = blockIdx.z;
  int d0 = blockIdx.y * 32, o0 = blockIdx.x * 32;
  int tx = threadIdx.x, ty = threadIdx.y;           // 32 x 8
  const float* src = gcn + (size_t)l * 589824;
  u16* dst = (l == 0) ? (QHB + (size_t)1536 * 768) : gcnT1;
  for (int i = 0; i < 32; i += 8) tile[ty + i][tx] = src[(size_t)(d0 + ty + i) * 768 + o0 + tx];
  __syncthreads();
  for (int i = 0; i < 32; i += 8) dst[(size_t)(o0 + ty + i) * 768 + d0 + tx] = f2bf(tile[tx][ty + i]);
}

// ---------- main GEMM: C[m][n] = sum_k A[m][k]*B[n][k] + bias[n] ----------
// 128x128 tile, BK=32. B staged via global_load_lds w/ XOR chunk swizzle (0 conflicts).
// AF32: A is fp32, converted to bf16 in-register during staging (kills the convert pass).
template<bool AF32>
__global__ void __launch_bounds__(256) gemm_bt(const void* __restrict__ Aptr, const u16* __restrict__ Bw,
                                               const float* __restrict__ bias, u16* __restrict__ C,
                                               int M, int N, int K)
{
  __shared__ __attribute__((aligned(16))) u16 As[128 * 32];
  __shared__ __attribute__((aligned(16))) u16 Bs[128 * 32];
  int tid = threadIdx.x, lane = tid & 63, wid = tid >> 6;
  int wm = wid >> 1, wn = wid & 1;
  size_t m0 = (size_t)blockIdx.x * 128, n0 = (size_t)blockIdx.y * 128;

  float4v acc[4][4];
  for (int r = 0; r < 4; r++) for (int c = 0; c < 4; c++) acc[r][c] = (float4v){0.f, 0.f, 0.f, 0.f};

  int srow = 32 * wid + (lane >> 2);
  int sq   = (lane & 3) ^ ((lane >> 3) & 3);        // fetched chunk for slot lane&3
  const u16*  gB  = Bw + (n0 + srow) * (size_t)K + sq * 8;
  u16* lB = &Bs[1024 * wid];
  const float* gAf0 = AF32 ? ((const float*)Aptr + (m0 + srow) * (size_t)K + sq * 8) : nullptr;
  const float* gAf1 = AF32 ? ((const float*)Aptr + (m0 + srow + 16) * (size_t)K + sq * 8) : nullptr;
  const u16*  gA16 = AF32 ? nullptr : ((const u16*)Aptr + (m0 + srow) * (size_t)K + sq * 8);
  u16* lA = &As[1024 * wid];
  int wslot16 = srow * 32 + (lane & 3) * 8;          // u16 idx of this lane's 16B slot (row srow)

  int l15 = lane & 15;
  int rs  = (lane >> 4) ^ ((lane >> 1) & 3);

  for (int kt = 0; kt < K; kt += 32) {
    if (AF32) {
      float4 f0 = *(const float4*)(gAf0 + kt);
      float4 f1 = *(const float4*)(gAf0 + kt + 4);
      float4 f2 = *(const float4*)(gAf1 + kt);
      float4 f3 = *(const float4*)(gAf1 + kt + 4);
      async16(gB + kt, lB);
      async16(gB + kt + (size_t)16 * K, lB + 512);
      uint4 o0 = { pack2(f0.x,f0.y), pack2(f0.z,f0.w), pack2(f1.x,f1.y), pack2(f1.z,f1.w) };
      uint4 o1 = { pack2(f2.x,f2.y), pack2(f2.z,f2.w), pack2(f3.x,f3.y), pack2(f3.z,f3.w) };
      *(uint4*)&As[wslot16]            = o0;
      *(uint4*)&As[wslot16 + 16 * 32]  = o1;
    } else {
      async16(gA16 + kt, lA);
      async16(gA16 + kt + (size_t)16 * K, lA + 512);
      async16(gB + kt, lB);
      async16(gB + kt + (size_t)16 * K, lB + 512);
    }
    __syncthreads();
    short8 af[4], bfr[4];
    for (int r = 0; r < 4; r++) af[r]  = *(const short8*)&As[(wm * 64 + r * 16 + l15) * 32 + rs * 8];
    for (int c = 0; c < 4; c++) bfr[c] = *(const short8*)&Bs[(wn * 64 + c * 16 + l15) * 32 + rs * 8];
    for (int r = 0; r < 4; r++)
      for (int c = 0; c < 4; c++)
        acc[r][c] = __builtin_amdgcn_mfma_f32_16x16x32_bf16(af[r], bfr[c], acc[r][c], 0, 0, 0);
    __syncthreads();
  }

  int quad = lane >> 4;
  for (int c = 0; c < 4; c++) {
    int n = (int)n0 + wn * 64 + c * 16 + l15;
    float bv = bias ? bias[n] : 0.f;
    for (int r = 0; r < 4; r++) {
      size_t mbase = m0 + wm * 64 + r * 16 + quad * 4;
      for (int t = 0; t < 4; t++)
        C[(mbase + t) * (size_t)N + n] = f2bf(acc[r][c][t] + bv);
    }
  }
}

// ================= fused per-graph adjacency kernels =================
// QH rows (stride 2304): [0,768)=Q, [768,1536)=K, [1536,2304)=H1.
// L1: S=Q.K^T per-wave direct-from-global MFMA (no barriers) -> rowsum via shfl+LDS atomics
//     -> adj bf16 (LDS + global) -> X1 = relu(LN(adj@H1)) via chunked HT transpose.
// L2: load adj -> relu(LN(adj@H2)) -> column mean only.

template<int NP>
__global__ void __launch_bounds__(512) fused_l1(const u16* __restrict__ QH,
                                                const float* __restrict__ lng, const float* __restrict__ lnb,
                                                u16* __restrict__ adjG, u16* __restrict__ X, int n)
{
  constexpr int ST = 72;
  constexpr int TPW = (NP == 64) ? 2 : 1;
  __shared__ __attribute__((aligned(16))) u16 adjb[NP * ST];
  __shared__ __attribute__((aligned(16))) u16 HT[64 * ST];
  __shared__ float rsum[NP];
  __shared__ float stats[NP][2];
  __shared__ float bc[NP][2];
  __shared__ float lg[768], lb[768];

  int g = blockIdx.x;
  int tid = threadIdx.x, lane = tid & 63, w = tid >> 6;
  int l15 = lane & 15, quad = lane >> 4;

  for (int i = tid; i < 768; i += 512) { lg[i] = lng[i]; lb[i] = lnb[i]; }
  if (tid < NP) { rsum[tid] = 0.f; stats[tid][0] = 0.f; stats[tid][1] = 0.f; }
  __syncthreads();

  // ---- stage 1: S = Q @ K^T, per-wave, no LDS/barriers ----
  int mt, nt0; bool s_act;
  if (NP == 64) { mt = w & 3; nt0 = (w >> 2) * 2; s_act = true; }
  else          { mt = w & 1; nt0 = w >> 1;       s_act = (w < 4); }

  int rowA = mt * 16 + l15;
  bool aok = rowA < n;
  const u16* pA  = QH + ((size_t)g * n + rowA) * 2304 + quad * 8;
  int rowB0 = (nt0) * 16 + l15, rowB1 = (nt0 + TPW - 1) * 16 + l15;
  bool b0ok = rowB0 < n, b1ok = rowB1 < n;
  const u16* pB0 = QH + ((size_t)g * n + rowB0) * 2304 + 768 + quad * 8;
  const u16* pB1 = QH + ((size_t)g * n + rowB1) * 2304 + 768 + quad * 8;

  float4v sacc[TPW];
  for (int j = 0; j < TPW; j++) sacc[j] = (float4v){0.f, 0.f, 0.f, 0.f};

  if (s_act) {
    for (int kt = 0; kt < 768; kt += 32) {
      uint4 av = {0,0,0,0}, bv0 = {0,0,0,0}, bv1 = {0,0,0,0};
      if (aok)  av  = *(const uint4*)(pA + kt);
      if (b0ok) bv0 = *(const uint4*)(pB0 + kt);
      if (TPW == 2 && b1ok) bv1 = *(const uint4*)(pB1 + kt);
      short8 a = *(short8*)&av;
      sacc[0] = __builtin_amdgcn_mfma_f32_16x16x32_bf16(a, *(short8*)&bv0, sacc[0], 0, 0, 0);
      if (TPW == 2)
        sacc[1] = __builtin_amdgcn_mfma_f32_16x16x32_bf16(a, *(short8*)&bv1, sacc[1], 0, 0, 0);
    }
    // partial row sums of S^2 (reduce over the 16 cols held across l15 lanes)
    for (int t = 0; t < 4; t++) {
      float s = 0.f;
      for (int j = 0; j < TPW; j++) { float v = sacc[j][t]; s += v * v; }
      s += __shfl_xor(s, 1); s += __shfl_xor(s, 2); s += __shfl_xor(s, 4); s += __shfl_xor(s, 8);
      if (l15 == 0) atomicAdd(&rsum[mt * 16 + quad * 4 + t], s);
    }
  }
  __syncthreads();
  if (tid < NP) rsum[tid] = 1.0f / fmaxf(rsum[tid], 1e-12f);
  __syncthreads();
  if (s_act) {
    u16* gadj = adjG + (size_t)g * NP * NP;
    for (int j = 0; j < TPW; j++)
      for (int t = 0; t < 4; t++) {
        int row = mt * 16 + quad * 4 + t, col = (nt0 + j) * 16 + l15;
        float v = sacc[j][t];
        u16 b = f2bf(v * v * rsum[row]);
        adjb[row * ST + col] = b;
        gadj[row * NP + col] = b;
      }
  }
  __syncthreads();

  // ---- stage 2: X = adj @ H1, 12 chunks of 64 d-cols ----
  int m2, nt20;
  if (NP == 64) { m2 = w & 3; nt20 = (w >> 2) * 2; }
  else          { m2 = w & 1; nt20 = w >> 1; }

  float4v xacc[12][TPW];
#pragma unroll
  for (int ch = 0; ch < 12; ch++) for (int j = 0; j < TPW; j++) xacc[ch][j] = (float4v){0.f,0.f,0.f,0.f};

  // transpose mapping: hj = node (fast across lanes -> banks spread), hseg = d-octet
  int hj  = tid & (NP - 1);
  int hseg= (NP == 64) ? w : ((tid >> 5) & 7);
  bool hact = (NP == 64) ? true : (tid < NP * 8);

#pragma unroll
  for (int ch = 0; ch < 12; ch++) {
    uint4 hv = {0,0,0,0};
    if (hact && hj < n) hv = *(const uint4*)(QH + ((size_t)g * n + hj) * 2304 + 1536 + ch * 64 + hseg * 8);
    __syncthreads();                      // prev chunk's HT reads complete
    if (hact) {
      const u16* ep = (const u16*)&hv;
      for (int i = 0; i < 8; i++) HT[(hseg * 8 + i) * ST + hj] = ep[i];
    }
    __syncthreads();
    for (int k = 0; k < NP / 32; k++) {
      short8 a = *(const short8*)&adjb[(m2 * 16 + l15) * ST + k * 32 + quad * 8];
      for (int j = 0; j < TPW; j++) {
        short8 b = *(const short8*)&HT[((nt20 + j) * 16 + l15) * ST + k * 32 + quad * 8];
        xacc[ch][j] = __builtin_amdgcn_mfma_f32_16x16x32_bf16(a, b, xacc[ch][j], 0, 0, 0);
      }
    }
  }

  // ---- LN stats ----
  float ssum[4] = {0,0,0,0}, ssq[4] = {0,0,0,0};
#pragma unroll
  for (int ch = 0; ch < 12; ch++)
    for (int j = 0; j < TPW; j++)
      for (int t = 0; t < 4; t++) { float v = xacc[ch][j][t]; ssum[t] += v; ssq[t] += v * v; }
  for (int m = 1; m <= 8; m <<= 1)
    for (int t = 0; t < 4; t++) { ssum[t] += __shfl_xor(ssum[t], m); ssq[t] += __shfl_xor(ssq[t], m); }
  if (l15 == 0)
    for (int t = 0; t < 4; t++) {
      atomicAdd(&stats[m2 * 16 + quad * 4 + t][0], ssum[t]);
      atomicAdd(&stats[m2 * 16 + quad * 4 + t][1], ssq[t]);
    }
  __syncthreads();
  if (tid < NP) {
    float mu = stats[tid][0] * (1.f / 768.f);
    float var = stats[tid][1] * (1.f / 768.f) - mu * mu;
    bc[tid][0] = mu; bc[tid][1] = rsqrtf(fmaxf(var, 0.f) + 1e-5f);
  }
  __syncthreads();

  // ---- LN + relu + write X ----
#pragma unroll
  for (int ch = 0; ch < 12; ch++)
    for (int j = 0; j < TPW; j++)
      for (int t = 0; t < 4; t++) {
        int row = m2 * 16 + quad * 4 + t;
        if (row < n) {
          int d = ch * 64 + (nt20 + j) * 16 + l15;
          float v = fmaxf((xacc[ch][j][t] - bc[row][0]) * bc[row][1] * lg[d] + lb[d], 0.f);
          X[((size_t)g * n + row) * 768 + d] = f2bf(v);
        }
      }
}

template<int NP>
__global__ void __launch_bounds__(512) fused_l2(const u16* __restrict__ adjG, const u16* __restrict__ H,
                                                const float* __restrict__ lng, const float* __restrict__ lnb,
                                                u16* __restrict__ Xmean, int n, float inv)
{
  constexpr int ST = 72;
  constexpr int TPW = (NP == 64) ? 2 : 1;
  __shared__ __attribute__((aligned(16))) u16 adjb[NP * ST];
  __shared__ __attribute__((aligned(16))) u16 HT[64 * ST];
  __shared__ float stats[NP][2];
  __shared__ float bc[NP][2];
  __shared__ float colsum[768];
  __shared__ float lg[768], lb[768];

  int g = blockIdx.x;
  int tid = threadIdx.x, lane = tid & 63, w = tid >> 6;
  int l15 = lane & 15, quad = lane >> 4;

  for (int i = tid; i < 768; i += 512) { lg[i] = lng[i]; lb[i] = lnb[i]; colsum[i] = 0.f; }
  if (tid < NP) { stats[tid][0] = 0.f; stats[tid][1] = 0.f; }
  if (tid * 8 < NP * NP) {
    int row = (tid * 8) / NP, c0 = (tid * 8) % NP;
    uint4 v = *(const uint4*)(adjG + (size_t)g * NP * NP + row * NP + c0);
    *(uint4*)&adjb[row * ST + c0] = v;
  }

  int m2, nt20;
  if (NP == 64) { m2 = w & 3; nt20 = (w >> 2) * 2; }
  else          { m2 = w & 1; nt20 = w >> 1; }

  float4v xacc[12][TPW];
#pragma unroll
  for (int ch = 0; ch < 12; ch++) for (int j = 0; j < TPW; j++) xacc[ch][j] = (float4v){0.f,0.f,0.f,0.f};

  int hj  = tid & (NP - 1);
  int hseg= (NP == 64) ? w : ((tid >> 5) & 7);
  bool hact = (NP == 64) ? true : (tid < NP * 8);

#pragma unroll
  for (int ch = 0; ch < 12; ch++) {
    uint4 hv = {0,0,0,0};
    if (hact && hj < n) hv = *(const uint4*)(H + ((size_t)g * n + hj) * 768 + ch * 64 + hseg * 8);
    __syncthreads();
    if (hact) {
      const u16* ep = (const u16*)&hv;
      for (int i = 0; i < 8; i++) HT[(hseg * 8 + i) * ST + hj] = ep[i];
    }
    __syncthreads();
    for (int k = 0; k < NP / 32; k++) {
      short8 a = *(const short8*)&adjb[(m2 * 16 + l15) * ST + k * 32 + quad * 8];
      for (int j = 0; j < TPW; j++) {
        short8 b = *(const short8*)&HT[((nt20 + j) * 16 + l15) * ST + k * 32 + quad * 8];
        xacc[ch][j] = __builtin_amdgcn_mfma_f32_16x16x32_bf16(a, b, xacc[ch][j], 0, 0, 0);
      }
    }
  }

  float ssum[4] = {0,0,0,0}, ssq[4] = {0,0,0,0};
#pragma unroll
  for (int ch = 0; ch < 12; ch++)
    for (int j = 0; j < TPW; j++)
      for (int t = 0; t < 4; t++) { float v = xacc[ch][j][t]; ssum[t] += v; ssq[t] += v * v; }
  for (int m = 1; m <= 8; m <<= 1)
    for (int t = 0; t < 4; t++) { ssum[t] += __shfl_xor(ssum[t], m); ssq[t] += __shfl_xor(ssq[t], m); }
  if (l15 == 0)
    for (int t = 0; t < 4; t++) {
      atomicAdd(&stats[m2 * 16 + quad * 4 + t][0], ssum[t]);
      atomicAdd(&stats[m2 * 16 + quad * 4 + t][1], ssq[t]);
    }
  __syncthreads();
  if (tid < NP) {
    float mu = stats[tid][0] * (1.f / 768.f);
    float var = stats[tid][1] * (1.f / 768.f) - mu * mu;
    bc[tid][0] = mu; bc[tid][1] = rsqrtf(fmaxf(var, 0.f) + 1e-5f);
  }
  __syncthreads();

#pragma unroll
  for (int ch = 0; ch < 12; ch++)
    for (int j = 0; j < TPW; j++)
      for (int t = 0; t < 4; t++) {
        int row = m2 * 16 + quad * 4 + t;
        int d = ch * 64 + (nt20 + j) * 16 + l15;
        float v = fmaxf((xacc[ch][j][t] - bc[row][0]) * bc[row][1] * lg[d] + lb[d], 0.f);
        float vm = (row < n) ? v : 0.f;
        vm += __shfl_xor(vm, 16);
        vm += __shfl_xor(vm, 32);
        if (quad == 0) atomicAdd(&colsum[d], vm);
      }
  __syncthreads();
  if (tid < 384)
    ((u32*)Xmean)[(size_t)g * 384 + tid] = pack2(colsum[tid * 2] * inv, colsum[tid * 2 + 1] * inv);
}

// ---------- concat: y = [bf2f(Xm) ; fgs] fp32 (in d_out) ----------
__global__ void __launch_bounds__(384) concat_y(const u16* __restrict__ Xm,
                                                const float* __restrict__ fgs, float* __restrict__ yout)
{
  int b = blockIdx.x, tid = threadIdx.x;
  u32 u = ((const u32*)Xm)[(size_t)b * 384 + tid];
  int d0 = tid * 2;
  yout[(size_t)b * 1536 + d0]     = bflo(u);
  yout[(size_t)b * 1536 + d0 + 1] = bfhi(u);
  yout[(size_t)b * 1536 + 768 + d0]     = fgs[(size_t)b * 768 + d0];
  yout[(size_t)b * 1536 + 768 + d0 + 1] = fgs[(size_t)b * 768 + d0 + 1];
}

// ---------- classifier ----------
__global__ void __launch_bounds__(256) fc1_relu(const float* __restrict__ yout,
                                                const float* __restrict__ fc1w, const float* __restrict__ fc1b,
                                                float* __restrict__ h)
{
  int o = blockIdx.x * 4 + (threadIdx.x >> 6);
  int lane = threadIdx.x & 63;
  float acc[16];
  for (int b = 0; b < 16; b++) acc[b] = 0.f;
  const float4* wr = (const float4*)(fc1w + (size_t)o * 1536);
  for (int k4 = lane; k4 < 384; k4 += 64) {
    float4 wv = wr[k4];
    for (int b = 0; b < 16; b++) {
      float4 yv = ((const float4*)(yout + (size_t)b * 1536))[k4];
      acc[b] += wv.x * yv.x + wv.y * yv.y + wv.z * yv.z + wv.w * yv.w;
    }
  }
  for (int m = 1; m <= 32; m <<= 1)
    for (int b = 0; b < 16; b++) acc[b] += __shfl_xor(acc[b], m);
  if (lane < 16) h[(size_t)lane * 768 + o] = fmaxf(acc[lane] + fc1b[o], 0.f);
}

__global__ void __launch_bounds__(256) fc2_out(const float* __restrict__ h,
                                               const float* __restrict__ fc2w, const float* __restrict__ fc2b,
                                               float* __restrict__ logits)
{
  int o = blockIdx.x * 4 + (threadIdx.x >> 6);
  int lane = threadIdx.x & 63;
  float acc[16];
  for (int b = 0; b < 16; b++) acc[b] = 0.f;
  const float4* wr = (const float4*)(fc2w + (size_t)o * 768);
  for (int k4 = lane; k4 < 192; k4 += 64) {
    float4 wv = wr[k4];
    for (int b = 0; b < 16; b++) {
      float4 hv = ((const float4*)(h + (size_t)b * 768))[k4];
      acc[b] += wv.x * hv.x + wv.y * hv.y + wv.z * hv.z + wv.w * hv.w;
    }
  }
  for (int m = 1; m <= 32; m <<= 1)
    for (int b = 0; b < 16; b++) acc[b] += __shfl_xor(acc[b], m);
  if (lane < 16) logits[(size_t)lane * 400 + o] = acc[lane] + fc2b[o];
}

// ---------- launch ----------
extern "C" void kernel_launch(void* const* d_in, const int* in_sizes, int n_in,
                              void* d_out, int out_size, void* d_ws, size_t ws_size,
                              hipStream_t stream) {
  const float* feats = (const float*)d_in[0];
  const float* fgs   = (const float*)d_in[1];
  const float* wq_w  = (const float*)d_in[3];
  const float* wq_b  = (const float*)d_in[4];
  const float* wk_w  = (const float*)d_in[5];
  const float* wk_b  = (const float*)d_in[6];
  const float* gcn_w = (const float*)d_in[7];
  const float* ln_g  = (const float*)d_in[8];
  const float* ln_b  = (const float*)d_in[9];
  const float* fc1_w = (const float*)d_in[10];
  const float* fc1_b = (const float*)d_in[11];
  const float* fc2_w = (const float*)d_in[12];
  const float* fc2_b = (const float*)d_in[13];
  float* out  = (float*)d_out;
  float* yout = out + 16 * 400;               // y region: [16][1536] fp32

  char* ws = (char*)d_ws;
  size_t off = 0;
  auto alloc = [&](size_t b){ size_t r = off; off = (off + b + 255) & ~(size_t)255; return r; };
  // persistent (~10 MB)
  u16*  QHB    = (u16*) (ws + alloc((size_t)2304 * 768 * 2));    // [Wq;Wk;gcn0^T] bf16
  u16*  gcnT1  = (u16*) (ws + alloc((size_t)768 * 768 * 2));
  float* biasQH= (float*)(ws + alloc((size_t)2304 * 4));
  u16*  Xf     = (u16*) (ws + alloc((size_t)512 * 768 * 2));
  u16*  QHf    = (u16*) (ws + alloc((size_t)512 * 2304 * 2));
  u16*  X1f    = (u16*) (ws + alloc((size_t)512 * 768 * 2));
  u16*  H2f    = (u16*) (ws + alloc((size_t)512 * 768 * 2));
  u16*  adjFb  = (u16*) (ws + alloc((size_t)16 * 32 * 32 * 2));
  u16*  Xm     = (u16*) (ws + alloc((size_t)16 * 768 * 2));
  float* hbuf  = (float*)(ws + alloc((size_t)16 * 768 * 4));
  size_t base = off;

  // per-chunk: QHc [R][2304] + X1c [R][768] + adjGc [GC][64][64] bf16 (H2c aliases QHc)
  auto need = [&](int GC){
    size_t R = (size_t)GC * 50;
    return base + R * 2304 * 2 + 512 + R * 768 * 2 + 512 + (size_t)GC * 64 * 64 * 2 + 512;
  };
  int GC = 64;
  if (need(512) <= ws_size) GC = 512;
  else if (need(256) <= ws_size) GC = 256;
  else if (need(128) <= ws_size) GC = 128;
  int R = GC * 50;
  size_t off2 = base;
  auto alloc2 = [&](size_t b){ size_t r = off2; off2 = (off2 + b + 255) & ~(size_t)255; return r; };
  u16* QHc   = (u16*)(ws + alloc2((size_t)R * 2304 * 2));
  u16* X1c   = (u16*)(ws + alloc2((size_t)R * 768 * 2));
  u16* adjGc = (u16*)(ws + alloc2((size_t)GC * 64 * 64 * 2));
  u16* H2c   = QHc;                      // QH dead after fused_l1

  // prep
  prep_qkw<<<288, 256, 0, stream>>>(wq_w, wk_w, wq_b, wk_b, QHB, biasQH);
  prep_gcnT<<<dim3(24, 24, 2), dim3(32, 8), 0, stream>>>(gcn_w, QHB, gcnT1);

  // ---- object-level graph (512 graphs of n=50), chunked ----
  int nchunks = 512 / GC;
  for (int c = 0; c < nchunks; c++) {
    const float* fc = feats + (size_t)c * GC * 50 * 768;
    gemm_bt<true><<<dim3(R / 128, 18), 256, 0, stream>>>(fc, QHB, biasQH, QHc, R, 2304, 768);
    fused_l1<64><<<GC, 512, 0, stream>>>(QHc, ln_g, ln_b, adjGc, X1c, 50);
    gemm_bt<false><<<dim3(R / 128, 6), 256, 0, stream>>>(X1c, gcnT1, nullptr, H2c, R, 768, 768);
    fused_l2<64><<<GC, 512, 0, stream>>>(adjGc, H2c, ln_g + 768, ln_b + 768,
                                         Xf + (size_t)c * GC * 768, 50, 1.f / 50.f);
  }

  // ---- frame-level graph (16 graphs of n=32) ----
  gemm_bt<false><<<dim3(4, 18), 256, 0, stream>>>(Xf, QHB, biasQH, QHf, 512, 2304, 768);
  fused_l1<32><<<16, 512, 0, stream>>>(QHf, ln_g, ln_b, adjFb, X1f, 32);
  gemm_bt<false><<<dim3(4, 6), 256, 0, stream>>>(X1f, gcnT1, nullptr, H2f, 512, 768, 768);
  fused_l2<32><<<16, 512, 0, stream>>>(adjFb, H2f, ln_g + 768, ln_b + 768, Xm, 32, 1.f / 32.f);

  // ---- head ----
  concat_y<<<16, 384, 0, stream>>>(Xm, fgs, yout);
  fc1_relu<<<192, 256, 0, stream>>>(yout, fc1_w, fc1_b, hbuf);
  fc2_out<<<100, 256, 0, stream>>>(hbuf, fc2_w, fc2_b, out);
}